// Round 3
// baseline (3949.710 us; speedup 1.0000x reference)
//
#include <hip/hip_runtime.h>

// ---------------------------------------------------------------------------
// 2-branch LSTM-CTC transcriber for MI355X.  B=32, T=1024, F=40, H=256.
//
// Round-3 change vs round-2 (one variable):
//  * Pin the per-thread recurrent-weight slice into VGPRs with
//    asm volatile("" : "+v"(w)) after the initial load. Round-2 compiled to
//    VGPR_Count=112 (< the 128 floats of w alone): LLVM rematerialized the
//    weight loads inside the step loop => 256 KB/wg/step from L2 (~3900
//    cyc/step at ~67 B/cyc/CU), which dominated the 2.1 us/step. An
//    asm-defined value cannot be rematerialized, forcing register residency.
//    Budget: __launch_bounds__(512,2) -> 256 VGPR/thread; est. live ~215.
// ---------------------------------------------------------------------------

#define HID 256
#define TT  1024
#define TP  342
#define FF  40

typedef float f32x4 __attribute__((ext_vector_type(4)));

__device__ __forceinline__ float sigf(float x)     { return 1.0f / (1.0f + __expf(-x)); }
__device__ __forceinline__ float tanhfast(float x) { return 1.0f - 2.0f / (__expf(2.0f * x) + 1.0f); }

#define PIN(v) asm volatile("" : "+v"(v))

// device-coherent (sc0 sc1) primitives -------------------------------------
__device__ __forceinline__ unsigned coh_load_u32(const unsigned* p) {
    unsigned v;
    asm volatile("global_load_dword %0, %1, off sc0 sc1\n\t"
                 "s_waitcnt vmcnt(0)"
                 : "=v"(v) : "v"(p) : "memory");
    return v;
}
__device__ __forceinline__ void coh_store_f32(float* p, float v) {
    asm volatile("global_store_dword %0, %1, off sc0 sc1"
                 :: "v"(p), "v"(v) : "memory");
}
__device__ __forceinline__ void coh_store_u32(unsigned* p, unsigned v) {
    asm volatile("global_store_dword %0, %1, off sc0 sc1"
                 :: "v"(p), "v"(v) : "memory");
}
__device__ __forceinline__ void wait_vm0() {
    asm volatile("s_waitcnt vmcnt(0)" ::: "memory");
}
// load 32 consecutive floats (8 x dwordx4), device-coherent, one waitcnt
__device__ __forceinline__ void coh_load_h32(const float* p, f32x4 (&a)[8]) {
    asm volatile(
        "global_load_dwordx4 %0, %8, off sc0 sc1\n\t"
        "global_load_dwordx4 %1, %8, off offset:16 sc0 sc1\n\t"
        "global_load_dwordx4 %2, %8, off offset:32 sc0 sc1\n\t"
        "global_load_dwordx4 %3, %8, off offset:48 sc0 sc1\n\t"
        "global_load_dwordx4 %4, %8, off offset:64 sc0 sc1\n\t"
        "global_load_dwordx4 %5, %8, off offset:80 sc0 sc1\n\t"
        "global_load_dwordx4 %6, %8, off offset:96 sc0 sc1\n\t"
        "global_load_dwordx4 %7, %8, off offset:112 sc0 sc1\n\t"
        "s_waitcnt vmcnt(0)"
        : "=&v"(a[0]), "=&v"(a[1]), "=&v"(a[2]), "=&v"(a[3]),
          "=&v"(a[4]), "=&v"(a[5]), "=&v"(a[6]), "=&v"(a[7])
        : "v"(p) : "memory");
}

// ---------------- LSTM layer 1 (input = clipped x, fused maxpool) ----------
__global__ __launch_bounds__(512, 2) void lstm1_kernel(
    const float* __restrict__ x, const int* __restrict__ x_len,
    const float* __restrict__ Wk_s, const float* __restrict__ Wr_s, const float* __restrict__ b_s,
    const float* __restrict__ Wk_c, const float* __restrict__ Wr_c, const float* __restrict__ b_c,
    float* __restrict__ hbuf,          // [2][64][256] (zeroed)
    unsigned* __restrict__ flags,      // [64][64]     (zeroed; flag at [grp][q*16])
    float* __restrict__ pooled)        // [2][32][342][256]
{
    const int blk = blockIdx.x;        // 0..255
    const int q   = blk >> 6;          // quarter 0..3
    const int grp = blk & 63;          // (branch, sample)
    const int br  = grp >> 5;
    const int s   = grp & 31;
    const int tid = threadIdx.x;
    const int u   = tid & 63;          // unit within quarter
    const int rg  = tid >> 6;          // row-group 0..7 (32 h-rows each)
    const int col0 = q * 64 + u;       // output unit index within H
    const int myq  = rg >> 1;          // the h-quarter my rows live in

    const float* Wk = br ? Wk_c : Wk_s;
    const float* Wr = br ? Wr_c : Wr_s;
    const float* bb = br ? b_c  : b_s;

    // Recurrent weight slice: w[g][k] = Wr[rg*32+k][g*256+col0]  (registers)
    float w[4][32];
#pragma unroll
    for (int g = 0; g < 4; ++g)
#pragma unroll
        for (int k = 0; k < 32; ++k) {
            w[g][k] = Wr[(size_t)(rg * 32 + k) * 1024 + g * 256 + col0];
            PIN(w[g][k]);              // forbid rematerialization
        }

    // Input-kernel slice: rows rg*8..rg*8+7 (rg<5 covers F=40)
    float wk[4][8];
    if (rg < 5) {
#pragma unroll
        for (int g = 0; g < 4; ++g)
#pragma unroll
            for (int j = 0; j < 8; ++j) {
                wk[g][j] = Wk[(size_t)(rg * 8 + j) * 1024 + g * 256 + col0];
                PIN(wk[g][j]);
            }
    }

    float bias[4] = {0.f, 0.f, 0.f, 0.f};
    if (rg == 0) {
#pragma unroll
        for (int g = 0; g < 4; ++g) bias[g] = bb[g * 256 + col0];
    }

    const int len = x_len[s];
    float cst = 0.f, hcur = 0.f, pm = -1e30f;

    __shared__ float part[8][4][64];
    const unsigned* myflag = flags + grp * 64 + myq * 16;
    unsigned* pubflag = (unsigned*)(flags + grp * 64 + q * 16);

    for (int t = 0; t < TT; ++t) {
        if (t < len) {
            // 1) independent input contribution (off critical path)
            float acc[4] = {0.f, 0.f, 0.f, 0.f};
            if (rg < 5) {
                const float* xr = x + ((size_t)s * TT + t) * FF + rg * 8;
#pragma unroll
                for (int j = 0; j < 8; ++j) {
                    float v = xr[j];
                    v = fminf(fmaxf(v, -3.f), 3.f);   // clip(x,-3,3)
#pragma unroll
                    for (int g = 0; g < 4; ++g) acc[g] += v * wk[g][j];
                }
            }
            // 2) wait for my h-quarter of step t, then load my 32 rows
            while (coh_load_u32(myflag) < (unsigned)t) { }
            const float* hr = hbuf + ((size_t)(t & 1) * 64 + grp) * 256 + rg * 32;
            f32x4 hv[8];
            coh_load_h32(hr, hv);

            // 3) partial z for my rows
#pragma unroll
            for (int i = 0; i < 8; ++i) {
#pragma unroll
                for (int jj = 0; jj < 4; ++jj) {
                    float hh = hv[i][jj];
#pragma unroll
                    for (int g = 0; g < 4; ++g)
                        acc[g] += hh * w[g][i * 4 + jj];
                }
            }
#pragma unroll
            for (int g = 0; g < 4; ++g) part[rg][g][u] = acc[g];
            __syncthreads();

            // 4) gate math + publish h quarter (wave rg==0 only)
            if (rg == 0) {
                float z[4];
#pragma unroll
                for (int g = 0; g < 4; ++g) {
                    float sum = bias[g];
#pragma unroll
                    for (int r = 0; r < 8; ++r) sum += part[r][g][u];
                    z[g] = sum;
                }
                float ig = sigf(z[0]);
                float fg = sigf(z[1]);
                float gg = tanhfast(z[2]);
                float og = sigf(z[3]);
                cst  = fg * cst + ig * gg;
                hcur = og * tanhfast(cst);
                float* hw = hbuf + ((size_t)((t + 1) & 1) * 64 + grp) * 256;
                coh_store_f32(hw + col0, hcur);        // write-through to L3
                wait_vm0();                            // h visible before flag
                if (u == 0) coh_store_u32(pubflag, (unsigned)(t + 1));
            }
            __syncthreads();   // keep LDS 'part' safe for next iteration
        }
        // fused maxpool3 stride3 SAME: window t' covers t in {3t'-1, 3t', 3t'+1}
        if (rg == 0) {
            pm = fmaxf(pm, hcur);
            if ((t % 3) == 1) {
                int tp = (t - 1) / 3;
                pooled[(((size_t)br * 32 + s) * TP + tp) * HID + col0] = pm;
                pm = -1e30f;
            }
        }
    }
    if (rg == 0)   // final window t'=341 covers t=1022,1023
        pooled[(((size_t)br * 32 + s) * TP + 341) * HID + col0] = pm;
}

// ---------------- LSTM layers 2/3 (input projection precomputed) -----------
__global__ __launch_bounds__(512, 2) void lstm23_kernel(
    const float* __restrict__ xz,      // [2][32][342][1024] (bias folded in)
    const int* __restrict__ x_len,
    const float* __restrict__ Wr_s, const float* __restrict__ Wr_c,
    float* __restrict__ hbuf, unsigned* __restrict__ flags,
    float* __restrict__ yout)          // [2][32][342][256]
{
    const int blk = blockIdx.x;
    const int q   = blk >> 6;
    const int grp = blk & 63;
    const int br  = grp >> 5;
    const int s   = grp & 31;
    const int tid = threadIdx.x;
    const int u   = tid & 63;
    const int rg  = tid >> 6;
    const int col0 = q * 64 + u;
    const int myq  = rg >> 1;

    const float* Wr = br ? Wr_c : Wr_s;

    float w[4][32];
#pragma unroll
    for (int g = 0; g < 4; ++g)
#pragma unroll
        for (int k = 0; k < 32; ++k) {
            w[g][k] = Wr[(size_t)(rg * 32 + k) * 1024 + g * 256 + col0];
            PIN(w[g][k]);
        }

    const int len = (x_len[s] + 2) / 3;   // seq_len after pool
    float cst = 0.f, hcur = 0.f;

    __shared__ float part[8][4][64];
    const unsigned* myflag = flags + grp * 64 + myq * 16;
    unsigned* pubflag = (unsigned*)(flags + grp * 64 + q * 16);

    for (int t = 0; t < TP; ++t) {
        const size_t row = ((size_t)br * 32 + s) * TP + t;
        if (t < len) {
            // independent input projection (rg==0 lanes) — issue before poll
            float xzv[4] = {0.f, 0.f, 0.f, 0.f};
            if (rg == 0) {
#pragma unroll
                for (int g = 0; g < 4; ++g)
                    xzv[g] = xz[row * 1024 + g * 256 + col0];
            }
            while (coh_load_u32(myflag) < (unsigned)t) { }
            const float* hr = hbuf + ((size_t)(t & 1) * 64 + grp) * 256 + rg * 32;
            f32x4 hv[8];
            coh_load_h32(hr, hv);

            float acc[4] = {0.f, 0.f, 0.f, 0.f};
#pragma unroll
            for (int i = 0; i < 8; ++i) {
#pragma unroll
                for (int jj = 0; jj < 4; ++jj) {
                    float hh = hv[i][jj];
#pragma unroll
                    for (int g = 0; g < 4; ++g)
                        acc[g] += hh * w[g][i * 4 + jj];
                }
            }
#pragma unroll
            for (int g = 0; g < 4; ++g) part[rg][g][u] = acc[g];
            __syncthreads();

            if (rg == 0) {
                float z[4];
#pragma unroll
                for (int g = 0; g < 4; ++g) {
                    float sum = xzv[g];
#pragma unroll
                    for (int r = 0; r < 8; ++r) sum += part[r][g][u];
                    z[g] = sum;
                }
                float ig = sigf(z[0]);
                float fg = sigf(z[1]);
                float gg = tanhfast(z[2]);
                float og = sigf(z[3]);
                cst  = fg * cst + ig * gg;
                hcur = og * tanhfast(cst);
                float* hw = hbuf + ((size_t)((t + 1) & 1) * 64 + grp) * 256;
                coh_store_f32(hw + col0, hcur);
                wait_vm0();
                if (u == 0) coh_store_u32(pubflag, (unsigned)(t + 1));
            }
            __syncthreads();
        }
        if (rg == 0)
            yout[row * HID + col0] = hcur;   // carried value when masked
    }
}

// ---------------- xz = A @ Wk + b (per-branch weights) ---------------------
// A: (21888, 256) rows 0..10943 branch s, 10944.. branch c. out: (21888, 1024)
__global__ __launch_bounds__(256) void gemm_xz(
    const float* __restrict__ A,
    const float* __restrict__ Ws, const float* __restrict__ Wc,
    const float* __restrict__ bs, const float* __restrict__ bc,
    float* __restrict__ out)
{
    __shared__ float As[32][68];    // [k][m], padded
    __shared__ float Bs[32][132];   // [k][n], padded
    const int tid = threadIdx.x;
    const int bx = blockIdx.x, by = blockIdx.y;   // 8 x 342
    const int row0 = by * 64, col0 = bx * 128;
    const int br = (by >= 171);
    const float* W    = br ? Wc : Ws;
    const float* bias = br ? bc : bs;
    const int tx = tid & 15, ty = tid >> 4;

    float acc[4][8];
#pragma unroll
    for (int i = 0; i < 4; ++i)
#pragma unroll
        for (int j = 0; j < 8; ++j) acc[i][j] = 0.f;

    for (int k0 = 0; k0 < 256; k0 += 32) {
#pragma unroll
        for (int i = 0; i < 2; ++i) {              // A tile 64x32, store transposed
            int c = tid * 2 + i;
            int r = c >> 3, kv = c & 7;
            float4 v = *(const float4*)(A + (size_t)(row0 + r) * 256 + k0 + kv * 4);
            As[kv * 4 + 0][r] = v.x; As[kv * 4 + 1][r] = v.y;
            As[kv * 4 + 2][r] = v.z; As[kv * 4 + 3][r] = v.w;
        }
#pragma unroll
        for (int i = 0; i < 4; ++i) {              // B tile 32x128
            int c = tid + i * 256;
            int kr = c >> 5, nv = c & 31;
            *(float4*)&Bs[kr][nv * 4] =
                *(const float4*)(W + (size_t)(k0 + kr) * 1024 + col0 + nv * 4);
        }
        __syncthreads();
#pragma unroll
        for (int k = 0; k < 32; ++k) {
            float4 a  = *(const float4*)&As[k][ty * 4];
            float4 b0 = *(const float4*)&Bs[k][tx * 8];
            float4 b1 = *(const float4*)&Bs[k][tx * 8 + 4];
            float av[4] = {a.x, a.y, a.z, a.w};
            float bv[8] = {b0.x, b0.y, b0.z, b0.w, b1.x, b1.y, b1.z, b1.w};
#pragma unroll
            for (int i = 0; i < 4; ++i)
#pragma unroll
                for (int j = 0; j < 8; ++j)
                    acc[i][j] += av[i] * bv[j];
        }
        __syncthreads();
    }
    float bv[8];
#pragma unroll
    for (int j = 0; j < 8; ++j) bv[j] = bias[col0 + tx * 8 + j];
#pragma unroll
    for (int i = 0; i < 4; ++i) {
        int r = row0 + ty * 4 + i;
        float4 o0 = {acc[i][0] + bv[0], acc[i][1] + bv[1], acc[i][2] + bv[2], acc[i][3] + bv[3]};
        float4 o1 = {acc[i][4] + bv[4], acc[i][5] + bv[5], acc[i][6] + bv[6], acc[i][7] + bv[7]};
        float* po = out + (size_t)r * 1024 + col0 + tx * 8;
        *(float4*)(po)     = o0;
        *(float4*)(po + 4) = o1;
    }
}

// ---------------- CTC projection -------------------------------------------
__global__ __launch_bounds__(256) void ctc_kernel(
    const float* __restrict__ Y,      // (21888, 256)
    const float* __restrict__ Wct,    // (256, 30)
    const float* __restrict__ bct,    // (30)
    float* __restrict__ dout)
{
    __shared__ float wl[256 * 30];
    __shared__ float yl[8][257];
    const int tid = threadIdx.x;
    const int row0 = blockIdx.x * 8;

    for (int i = tid; i < 7680; i += 256) wl[i] = Wct[i];
#pragma unroll
    for (int i = 0; i < 8; ++i) {
        int c = tid + i * 256;
        int r = c >> 8, k = c & 255;
        yl[r][k] = Y[(size_t)(row0 + r) * 256 + k];
    }
    __syncthreads();

    const int v = tid & 31, r = tid >> 5;
    if (v < 30) {
        float acc = bct[v];
#pragma unroll 8
        for (int k = 0; k < 256; ++k) acc += yl[r][k] * wl[k * 30 + v];
        int gr = row0 + r;
        int br = gr / 10944;
        int rr = gr - br * 10944;
        dout[(br ? 328352 : 0) + (size_t)rr * 30 + v] = acc;
    }
}

// ---------------- lens + close flags ----------------------------------------
__global__ __launch_bounds__(256) void finalize_kernel(
    const int* __restrict__ x_len, float* __restrict__ dout)
{
    const int b = blockIdx.x, tid = threadIdx.x;
    const float* cs = dout + (size_t)b * 10260;
    const float* cc = dout + 328352 + (size_t)b * 10260;
    __shared__ int flag;
    if (tid == 0) flag = 1;
    __syncthreads();
    bool ok = true;
    for (int i = tid; i < 10260; i += 256)
        ok &= (fabsf(cs[i] - cc[i]) < 1e-5f);
    if (!ok) atomicAnd(&flag, 0);
    __syncthreads();
    if (tid == 0) {
        float L = (float)((x_len[b] + 2) / 3);
        dout[328320 + b] = L;          // len_s
        dout[656672 + b] = L;          // len_c
        dout[656704 + b] = flag ? 1.0f : 0.0f;  // close
    }
}

// ---------------------------------------------------------------------------
extern "C" void kernel_launch(void* const* d_in, const int* in_sizes, int n_in,
                              void* d_out, int out_size, void* d_ws, size_t ws_size,
                              hipStream_t stream)
{
    (void)in_sizes; (void)n_in; (void)out_size;
    const float* x     = (const float*)d_in[0];
    const int*   x_len = (const int*)  d_in[1];
    const float* ws0_k = (const float*)d_in[2];
    const float* ws0_r = (const float*)d_in[3];
    const float* ws0_b = (const float*)d_in[4];
    const float* ws1_k = (const float*)d_in[5];
    const float* ws1_r = (const float*)d_in[6];
    const float* ws1_b = (const float*)d_in[7];
    const float* wc0_k = (const float*)d_in[8];
    const float* wc0_r = (const float*)d_in[9];
    const float* wc0_b = (const float*)d_in[10];
    const float* wc1_k = (const float*)d_in[11];
    const float* wc1_r = (const float*)d_in[12];
    const float* wc1_b = (const float*)d_in[13];
    const float* ctc_w = (const float*)d_in[14];
    const float* ctc_b = (const float*)d_in[15];
    float* out = (float*)d_out;
    char*  ws  = (char*)d_ws;

    // workspace layout
    const size_t flg_bytes = 3ull * 64 * 64 * sizeof(unsigned);        // 49152
    const size_t h_bytes   = 3ull * 2 * 64 * 256 * sizeof(float);      // 393216
    const size_t off_b0    = flg_bytes + h_bytes;                      // 442368
    const size_t b0_bytes  = 2ull * 32 * 342 * 256 * sizeof(float);    // 22.4 MB (pooled/ys2/ys3)
    const size_t off_b1    = off_b0 + b0_bytes;
    const size_t b1_bytes  = 2ull * 32 * 342 * 1024 * sizeof(float);   // 89.7 MB (xz)
    if (ws_size < off_b1 + b1_bytes) return;   // need ~112.5 MB

    unsigned* f1 = (unsigned*)ws;
    unsigned* f2 = f1 + 64 * 64;
    unsigned* f3 = f2 + 64 * 64;
    float* h1 = (float*)(ws + flg_bytes);
    float* h2 = h1 + 2 * 64 * 256;
    float* h3 = h2 + 2 * 64 * 256;
    float* buf0 = (float*)(ws + off_b0);
    float* buf1 = (float*)(ws + off_b1);

    // zero flags + h double-buffers (fresh every launch/replay)
    hipMemsetAsync(ws, 0, off_b0, stream);

    // LSTM1 + fused maxpool -> buf0 = pooled
    lstm1_kernel<<<256, 512, 0, stream>>>(x, x_len, ws0_k, ws0_r, ws0_b,
                                          wc0_k, wc0_r, wc0_b, h1, f1, buf0);
    // xz2 = pooled @ Wk1 + b1 -> buf1
    gemm_xz<<<dim3(8, 342), 256, 0, stream>>>(buf0, ws1_k, wc1_k, ws1_b, wc1_b, buf1);
    // LSTM2 -> buf0 = ys2
    lstm23_kernel<<<256, 512, 0, stream>>>(buf1, x_len, ws1_r, wc1_r, h2, f2, buf0);
    // xz3 = ys2 @ Wk1 + b1 -> buf1
    gemm_xz<<<dim3(8, 342), 256, 0, stream>>>(buf0, ws1_k, wc1_k, ws1_b, wc1_b, buf1);
    // LSTM3 -> buf0 = ys3
    lstm23_kernel<<<256, 512, 0, stream>>>(buf1, x_len, ws1_r, wc1_r, h3, f3, buf0);
    // CTC projection -> d_out ctc regions
    ctc_kernel<<<2736, 256, 0, stream>>>(buf0, ctc_w, ctc_b, out);
    // lens + close
    finalize_kernel<<<32, 256, 0, stream>>>(x_len, out);
}

// Round 4
// 3169.560 us; speedup vs baseline: 1.2461x; 1.2461x over previous
//
#include <hip/hip_runtime.h>

// ---------------------------------------------------------------------------
// 2-branch LSTM-CTC transcriber for MI355X.  B=32, T=1024, F=40, H=256.
//
// Round-4 changes vs round-3:
//  * REVERT round-3 PINs (regressed; weights already live in unified
//    VGPR/AGPR file — VGPR_Count=112 reports only the VGPR half).
//  * Tag-in-mantissa sync protocol: publish h with the step tag embedded in
//    the low 8 mantissa bits of every dword (masked off by consumers before
//    use; ~2^-16 relative truncation, deterministic). Consumers poll the h
//    data itself and accept when all 32 tags match. Removes BOTH the
//    producer-side s_waitcnt vmcnt(0) (store-ack round trip) and the
//    separate flag store + flag-poll round trip: 2 fewer serial L3 RTs/step.
//  * part[] LDS double-buffered by step parity -> second __syncthreads
//    removed (waves no longer wait for rg0's gate math each step).
// ---------------------------------------------------------------------------

#define HID 256
#define TT  1024
#define TP  342
#define FF  40

typedef float f32x4 __attribute__((ext_vector_type(4)));

__device__ __forceinline__ float sigf(float x)     { return 1.0f / (1.0f + __expf(-x)); }
__device__ __forceinline__ float tanhfast(float x) { return 1.0f - 2.0f / (__expf(2.0f * x) + 1.0f); }

// device-coherent (sc0 sc1) primitives -------------------------------------
__device__ __forceinline__ void coh_store_u32(unsigned* p, unsigned v) {
    asm volatile("global_store_dword %0, %1, off sc0 sc1"
                 :: "v"(p), "v"(v) : "memory");
}
// load 32 consecutive floats (8 x dwordx4), device-coherent, one waitcnt
__device__ __forceinline__ void coh_load_h32(const float* p, f32x4 (&a)[8]) {
    asm volatile(
        "global_load_dwordx4 %0, %8, off sc0 sc1\n\t"
        "global_load_dwordx4 %1, %8, off offset:16 sc0 sc1\n\t"
        "global_load_dwordx4 %2, %8, off offset:32 sc0 sc1\n\t"
        "global_load_dwordx4 %3, %8, off offset:48 sc0 sc1\n\t"
        "global_load_dwordx4 %4, %8, off offset:64 sc0 sc1\n\t"
        "global_load_dwordx4 %5, %8, off offset:80 sc0 sc1\n\t"
        "global_load_dwordx4 %6, %8, off offset:96 sc0 sc1\n\t"
        "global_load_dwordx4 %7, %8, off offset:112 sc0 sc1\n\t"
        "s_waitcnt vmcnt(0)"
        : "=&v"(a[0]), "=&v"(a[1]), "=&v"(a[2]), "=&v"(a[3]),
          "=&v"(a[4]), "=&v"(a[5]), "=&v"(a[6]), "=&v"(a[7])
        : "v"(p) : "memory");
}
// poll until all 32 dwords carry `tag` in their low byte
__device__ __forceinline__ void poll_h32(const float* p, unsigned tag, f32x4 (&hv)[8]) {
    unsigned m;
    do {
        coh_load_h32(p, hv);
        m = 0;
#pragma unroll
        for (int i = 0; i < 8; ++i)
#pragma unroll
            for (int j = 0; j < 4; ++j)
                m |= (__float_as_uint(hv[i][j]) ^ tag);
    } while (m & 0xFFu);
}
__device__ __forceinline__ float untag(float v) {
    return __uint_as_float(__float_as_uint(v) & 0xFFFFFF00u);
}

// ---------------- LSTM layer 1 (input = clipped x, fused maxpool) ----------
__global__ __launch_bounds__(512, 2) void lstm1_kernel(
    const float* __restrict__ x, const int* __restrict__ x_len,
    const float* __restrict__ Wk_s, const float* __restrict__ Wr_s, const float* __restrict__ b_s,
    const float* __restrict__ Wk_c, const float* __restrict__ Wr_c, const float* __restrict__ b_c,
    float* __restrict__ hbuf,          // [2][64][256] (zeroed -> h=0, tag=0)
    float* __restrict__ pooled)        // [2][32][342][256]
{
    const int blk = blockIdx.x;        // 0..255
    const int q   = blk >> 6;          // quarter 0..3
    const int grp = blk & 63;          // (branch, sample)
    const int br  = grp >> 5;
    const int s   = grp & 31;
    const int tid = threadIdx.x;
    const int u   = tid & 63;          // unit within quarter
    const int rg  = tid >> 6;          // row-group 0..7 (32 h-rows each)
    const int col0 = q * 64 + u;       // output unit index within H

    const float* Wk = br ? Wk_c : Wk_s;
    const float* Wr = br ? Wr_c : Wr_s;
    const float* bb = br ? b_c  : b_s;

    // Recurrent weight slice: w[g][k] = Wr[rg*32+k][g*256+col0]
    float w[4][32];
#pragma unroll
    for (int g = 0; g < 4; ++g)
#pragma unroll
        for (int k = 0; k < 32; ++k)
            w[g][k] = Wr[(size_t)(rg * 32 + k) * 1024 + g * 256 + col0];

    // Input-kernel slice: rows rg*8..rg*8+7 (rg<5 covers F=40)
    float wk[4][8];
    if (rg < 5) {
#pragma unroll
        for (int g = 0; g < 4; ++g)
#pragma unroll
            for (int j = 0; j < 8; ++j)
                wk[g][j] = Wk[(size_t)(rg * 8 + j) * 1024 + g * 256 + col0];
    }

    float bias[4] = {0.f, 0.f, 0.f, 0.f};
    if (rg == 0) {
#pragma unroll
        for (int g = 0; g < 4; ++g) bias[g] = bb[g * 256 + col0];
    }

    const int len = x_len[s];
    float cst = 0.f, hcur = 0.f, pm = -1e30f;

    __shared__ float part[2][8][4][64];   // step-parity double buffer

    for (int t = 0; t < TT; ++t) {
        if (t < len) {
            // 1) independent input contribution (off critical path)
            float acc[4] = {0.f, 0.f, 0.f, 0.f};
            if (rg < 5) {
                const float* xr = x + ((size_t)s * TT + t) * FF + rg * 8;
#pragma unroll
                for (int j = 0; j < 8; ++j) {
                    float v = xr[j];
                    v = fminf(fmaxf(v, -3.f), 3.f);   // clip(x,-3,3)
#pragma unroll
                    for (int g = 0; g < 4; ++g) acc[g] += v * wk[g][j];
                }
            }
            // 2) poll my 32 h rows of step t (tag = t&0xFF rides in the data)
            const float* hr = hbuf + ((size_t)(t & 1) * 64 + grp) * 256 + rg * 32;
            f32x4 hv[8];
            poll_h32(hr, (unsigned)t & 0xFFu, hv);

            // 3) partial z for my rows (mask tag bits off before use)
#pragma unroll
            for (int i = 0; i < 8; ++i) {
#pragma unroll
                for (int jj = 0; jj < 4; ++jj) {
                    float hh = untag(hv[i][jj]);
#pragma unroll
                    for (int g = 0; g < 4; ++g)
                        acc[g] += hh * w[g][i * 4 + jj];
                }
            }
#pragma unroll
            for (int g = 0; g < 4; ++g) part[t & 1][rg][g][u] = acc[g];
            __syncthreads();

            // 4) gate math + publish h quarter (wave rg==0 only)
            if (rg == 0) {
                float z[4];
#pragma unroll
                for (int g = 0; g < 4; ++g) {
                    float sum = bias[g];
#pragma unroll
                    for (int r = 0; r < 8; ++r) sum += part[t & 1][r][g][u];
                    z[g] = sum;
                }
                float ig = sigf(z[0]);
                float fg = sigf(z[1]);
                float gg = tanhfast(z[2]);
                float og = sigf(z[3]);
                cst  = fg * cst + ig * gg;
                hcur = og * tanhfast(cst);
                float* hw = hbuf + ((size_t)((t + 1) & 1) * 64 + grp) * 256;
                unsigned hb = (__float_as_uint(hcur) & 0xFFFFFF00u)
                            | ((unsigned)(t + 1) & 0xFFu);
                coh_store_u32((unsigned*)(hw + col0), hb);   // no wait, no flag
            }
            // no second __syncthreads: part[] is parity double-buffered
        }
        // fused maxpool3 stride3 SAME: window t' covers t in {3t'-1, 3t', 3t'+1}
        if (rg == 0) {
            pm = fmaxf(pm, hcur);
            if ((t % 3) == 1) {
                int tp = (t - 1) / 3;
                pooled[(((size_t)br * 32 + s) * TP + tp) * HID + col0] = pm;
                pm = -1e30f;
            }
        }
    }
    if (rg == 0)   // final window t'=341 covers t=1022,1023
        pooled[(((size_t)br * 32 + s) * TP + 341) * HID + col0] = pm;
}

// ---------------- LSTM layers 2/3 (input projection precomputed) -----------
__global__ __launch_bounds__(512, 2) void lstm23_kernel(
    const float* __restrict__ xz,      // [2][32][342][1024] (bias folded in)
    const int* __restrict__ x_len,
    const float* __restrict__ Wr_s, const float* __restrict__ Wr_c,
    float* __restrict__ hbuf,
    float* __restrict__ yout)          // [2][32][342][256]
{
    const int blk = blockIdx.x;
    const int q   = blk >> 6;
    const int grp = blk & 63;
    const int br  = grp >> 5;
    const int s   = grp & 31;
    const int tid = threadIdx.x;
    const int u   = tid & 63;
    const int rg  = tid >> 6;
    const int col0 = q * 64 + u;

    const float* Wr = br ? Wr_c : Wr_s;

    float w[4][32];
#pragma unroll
    for (int g = 0; g < 4; ++g)
#pragma unroll
        for (int k = 0; k < 32; ++k)
            w[g][k] = Wr[(size_t)(rg * 32 + k) * 1024 + g * 256 + col0];

    const int len = (x_len[s] + 2) / 3;   // seq_len after pool
    float cst = 0.f, hcur = 0.f;

    __shared__ float part[2][8][4][64];

    for (int t = 0; t < TP; ++t) {
        const size_t row = ((size_t)br * 32 + s) * TP + t;
        if (t < len) {
            // independent input projection (rg==0 lanes) — issue before poll
            float xzv[4] = {0.f, 0.f, 0.f, 0.f};
            if (rg == 0) {
#pragma unroll
                for (int g = 0; g < 4; ++g)
                    xzv[g] = xz[row * 1024 + g * 256 + col0];
            }
            const float* hr = hbuf + ((size_t)(t & 1) * 64 + grp) * 256 + rg * 32;
            f32x4 hv[8];
            poll_h32(hr, (unsigned)t & 0xFFu, hv);

            float acc[4] = {0.f, 0.f, 0.f, 0.f};
#pragma unroll
            for (int i = 0; i < 8; ++i) {
#pragma unroll
                for (int jj = 0; jj < 4; ++jj) {
                    float hh = untag(hv[i][jj]);
#pragma unroll
                    for (int g = 0; g < 4; ++g)
                        acc[g] += hh * w[g][i * 4 + jj];
                }
            }
#pragma unroll
            for (int g = 0; g < 4; ++g) part[t & 1][rg][g][u] = acc[g];
            __syncthreads();

            if (rg == 0) {
                float z[4];
#pragma unroll
                for (int g = 0; g < 4; ++g) {
                    float sum = xzv[g];
#pragma unroll
                    for (int r = 0; r < 8; ++r) sum += part[t & 1][r][g][u];
                    z[g] = sum;
                }
                float ig = sigf(z[0]);
                float fg = sigf(z[1]);
                float gg = tanhfast(z[2]);
                float og = sigf(z[3]);
                cst  = fg * cst + ig * gg;
                hcur = og * tanhfast(cst);
                float* hw = hbuf + ((size_t)((t + 1) & 1) * 64 + grp) * 256;
                unsigned hb = (__float_as_uint(hcur) & 0xFFFFFF00u)
                            | ((unsigned)(t + 1) & 0xFFu);
                coh_store_u32((unsigned*)(hw + col0), hb);
            }
        }
        if (rg == 0)
            yout[row * HID + col0] = hcur;   // carried value when masked
    }
}

// ---------------- xz = A @ Wk + b (per-branch weights) ---------------------
// A: (21888, 256) rows 0..10943 branch s, 10944.. branch c. out: (21888, 1024)
__global__ __launch_bounds__(256) void gemm_xz(
    const float* __restrict__ A,
    const float* __restrict__ Ws, const float* __restrict__ Wc,
    const float* __restrict__ bs, const float* __restrict__ bc,
    float* __restrict__ out)
{
    __shared__ float As[32][68];    // [k][m], padded
    __shared__ float Bs[32][132];   // [k][n], padded
    const int tid = threadIdx.x;
    const int bx = blockIdx.x, by = blockIdx.y;   // 8 x 342
    const int row0 = by * 64, col0 = bx * 128;
    const int br = (by >= 171);
    const float* W    = br ? Wc : Ws;
    const float* bias = br ? bc : bs;
    const int tx = tid & 15, ty = tid >> 4;

    float acc[4][8];
#pragma unroll
    for (int i = 0; i < 4; ++i)
#pragma unroll
        for (int j = 0; j < 8; ++j) acc[i][j] = 0.f;

    for (int k0 = 0; k0 < 256; k0 += 32) {
#pragma unroll
        for (int i = 0; i < 2; ++i) {              // A tile 64x32, store transposed
            int c = tid * 2 + i;
            int r = c >> 3, kv = c & 7;
            float4 v = *(const float4*)(A + (size_t)(row0 + r) * 256 + k0 + kv * 4);
            As[kv * 4 + 0][r] = v.x; As[kv * 4 + 1][r] = v.y;
            As[kv * 4 + 2][r] = v.z; As[kv * 4 + 3][r] = v.w;
        }
#pragma unroll
        for (int i = 0; i < 4; ++i) {              // B tile 32x128
            int c = tid + i * 256;
            int kr = c >> 5, nv = c & 31;
            *(float4*)&Bs[kr][nv * 4] =
                *(const float4*)(W + (size_t)(k0 + kr) * 1024 + col0 + nv * 4);
        }
        __syncthreads();
#pragma unroll
        for (int k = 0; k < 32; ++k) {
            float4 a  = *(const float4*)&As[k][ty * 4];
            float4 b0 = *(const float4*)&Bs[k][tx * 8];
            float4 b1 = *(const float4*)&Bs[k][tx * 8 + 4];
            float av[4] = {a.x, a.y, a.z, a.w};
            float bv[8] = {b0.x, b0.y, b0.z, b0.w, b1.x, b1.y, b1.z, b1.w};
#pragma unroll
            for (int i = 0; i < 4; ++i)
#pragma unroll
                for (int j = 0; j < 8; ++j)
                    acc[i][j] += av[i] * bv[j];
        }
        __syncthreads();
    }
    float bv[8];
#pragma unroll
    for (int j = 0; j < 8; ++j) bv[j] = bias[col0 + tx * 8 + j];
#pragma unroll
    for (int i = 0; i < 4; ++i) {
        int r = row0 + ty * 4 + i;
        float4 o0 = {acc[i][0] + bv[0], acc[i][1] + bv[1], acc[i][2] + bv[2], acc[i][3] + bv[3]};
        float4 o1 = {acc[i][4] + bv[4], acc[i][5] + bv[5], acc[i][6] + bv[6], acc[i][7] + bv[7]};
        float* po = out + (size_t)r * 1024 + col0 + tx * 8;
        *(float4*)(po)     = o0;
        *(float4*)(po + 4) = o1;
    }
}

// ---------------- CTC projection -------------------------------------------
__global__ __launch_bounds__(256) void ctc_kernel(
    const float* __restrict__ Y,      // (21888, 256)
    const float* __restrict__ Wct,    // (256, 30)
    const float* __restrict__ bct,    // (30)
    float* __restrict__ dout)
{
    __shared__ float wl[256 * 30];
    __shared__ float yl[8][257];
    const int tid = threadIdx.x;
    const int row0 = blockIdx.x * 8;

    for (int i = tid; i < 7680; i += 256) wl[i] = Wct[i];
#pragma unroll
    for (int i = 0; i < 8; ++i) {
        int c = tid + i * 256;
        int r = c >> 8, k = c & 255;
        yl[r][k] = Y[(size_t)(row0 + r) * 256 + k];
    }
    __syncthreads();

    const int v = tid & 31, r = tid >> 5;
    if (v < 30) {
        float acc = bct[v];
#pragma unroll 8
        for (int k = 0; k < 256; ++k) acc += yl[r][k] * wl[k * 30 + v];
        int gr = row0 + r;
        int br = gr / 10944;
        int rr = gr - br * 10944;
        dout[(br ? 328352 : 0) + (size_t)rr * 30 + v] = acc;
    }
}

// ---------------- lens + close flags ----------------------------------------
__global__ __launch_bounds__(256) void finalize_kernel(
    const int* __restrict__ x_len, float* __restrict__ dout)
{
    const int b = blockIdx.x, tid = threadIdx.x;
    const float* cs = dout + (size_t)b * 10260;
    const float* cc = dout + 328352 + (size_t)b * 10260;
    __shared__ int flag;
    if (tid == 0) flag = 1;
    __syncthreads();
    bool ok = true;
    for (int i = tid; i < 10260; i += 256)
        ok &= (fabsf(cs[i] - cc[i]) < 1e-5f);
    if (!ok) atomicAnd(&flag, 0);
    __syncthreads();
    if (tid == 0) {
        float L = (float)((x_len[b] + 2) / 3);
        dout[328320 + b] = L;          // len_s
        dout[656672 + b] = L;          // len_c
        dout[656704 + b] = flag ? 1.0f : 0.0f;  // close
    }
}

// ---------------------------------------------------------------------------
extern "C" void kernel_launch(void* const* d_in, const int* in_sizes, int n_in,
                              void* d_out, int out_size, void* d_ws, size_t ws_size,
                              hipStream_t stream)
{
    (void)in_sizes; (void)n_in; (void)out_size;
    const float* x     = (const float*)d_in[0];
    const int*   x_len = (const int*)  d_in[1];
    const float* ws0_k = (const float*)d_in[2];
    const float* ws0_r = (const float*)d_in[3];
    const float* ws0_b = (const float*)d_in[4];
    const float* ws1_k = (const float*)d_in[5];
    const float* ws1_r = (const float*)d_in[6];
    const float* ws1_b = (const float*)d_in[7];
    const float* wc0_k = (const float*)d_in[8];
    const float* wc0_r = (const float*)d_in[9];
    const float* wc0_b = (const float*)d_in[10];
    const float* wc1_k = (const float*)d_in[11];
    const float* wc1_r = (const float*)d_in[12];
    const float* wc1_b = (const float*)d_in[13];
    const float* ctc_w = (const float*)d_in[14];
    const float* ctc_b = (const float*)d_in[15];
    float* out = (float*)d_out;
    char*  ws  = (char*)d_ws;

    // workspace layout
    const size_t h_bytes  = 3ull * 2 * 64 * 256 * sizeof(float);      // 393216
    const size_t off_b0   = h_bytes;
    const size_t b0_bytes = 2ull * 32 * 342 * 256 * sizeof(float);    // 22.4 MB (pooled/ys2/ys3)
    const size_t off_b1   = off_b0 + b0_bytes;
    const size_t b1_bytes = 2ull * 32 * 342 * 1024 * sizeof(float);   // 89.7 MB (xz)
    if (ws_size < off_b1 + b1_bytes) return;   // need ~112 MB

    float* h1 = (float*)ws;
    float* h2 = h1 + 2 * 64 * 256;
    float* h3 = h2 + 2 * 64 * 256;
    float* buf0 = (float*)(ws + off_b0);
    float* buf1 = (float*)(ws + off_b1);

    // zero h double-buffers (h=0, tag=0 for t=0) — fresh every launch/replay
    hipMemsetAsync(ws, 0, h_bytes, stream);

    // LSTM1 + fused maxpool -> buf0 = pooled
    lstm1_kernel<<<256, 512, 0, stream>>>(x, x_len, ws0_k, ws0_r, ws0_b,
                                          wc0_k, wc0_r, wc0_b, h1, buf0);
    // xz2 = pooled @ Wk1 + b1 -> buf1
    gemm_xz<<<dim3(8, 342), 256, 0, stream>>>(buf0, ws1_k, wc1_k, ws1_b, wc1_b, buf1);
    // LSTM2 -> buf0 = ys2
    lstm23_kernel<<<256, 512, 0, stream>>>(buf1, x_len, ws1_r, wc1_r, h2, buf0);
    // xz3 = ys2 @ Wk1 + b1 -> buf1
    gemm_xz<<<dim3(8, 342), 256, 0, stream>>>(buf0, ws1_k, wc1_k, ws1_b, wc1_b, buf1);
    // LSTM3 -> buf0 = ys3
    lstm23_kernel<<<256, 512, 0, stream>>>(buf1, x_len, ws1_r, wc1_r, h3, buf0);
    // CTC projection -> d_out ctc regions
    ctc_kernel<<<2736, 256, 0, stream>>>(buf0, ctc_w, ctc_b, out);
    // lens + close
    finalize_kernel<<<32, 256, 0, stream>>>(x_len, out);
}

// Round 5
// 3124.934 us; speedup vs baseline: 1.2639x; 1.0143x over previous
//
#include <hip/hip_runtime.h>

// ---------------------------------------------------------------------------
// 2-branch LSTM-CTC transcriber for MI355X.  B=32, T=1024, F=40, H=256.
//
// Round-4 changes vs round-3:
//  * REVERT round-3 PINs (regressed; weights already live in unified
//    VGPR/AGPR file — VGPR_Count=112 reports only the VGPR half).
//  * Tag-in-mantissa sync protocol: publish h with the step tag embedded in
//    the low 8 mantissa bits of every dword (masked off by consumers before
//    use; ~2^-16 relative truncation, deterministic). Consumers poll the h
//    data itself and accept when all 32 tags match. Removes BOTH the
//    producer-side s_waitcnt vmcnt(0) (store-ack round trip) and the
//    separate flag store + flag-poll round trip: 2 fewer serial L3 RTs/step.
//  * part[] LDS double-buffered by step parity -> second __syncthreads
//    removed (waves no longer wait for rg0's gate math each step).
// ---------------------------------------------------------------------------

#define HID 256
#define TT  1024
#define TP  342
#define FF  40

typedef float f32x4 __attribute__((ext_vector_type(4)));

__device__ __forceinline__ float sigf(float x)     { return 1.0f / (1.0f + __expf(-x)); }
__device__ __forceinline__ float tanhfast(float x) { return 1.0f - 2.0f / (__expf(2.0f * x) + 1.0f); }

// device-coherent (sc0 sc1) primitives -------------------------------------
__device__ __forceinline__ void coh_store_u32(unsigned* p, unsigned v) {
    asm volatile("global_store_dword %0, %1, off sc0 sc1"
                 :: "v"(p), "v"(v) : "memory");
}
// load 32 consecutive floats (8 x dwordx4), device-coherent, one waitcnt
__device__ __forceinline__ void coh_load_h32(const float* p, f32x4 (&a)[8]) {
    asm volatile(
        "global_load_dwordx4 %0, %8, off sc0 sc1\n\t"
        "global_load_dwordx4 %1, %8, off offset:16 sc0 sc1\n\t"
        "global_load_dwordx4 %2, %8, off offset:32 sc0 sc1\n\t"
        "global_load_dwordx4 %3, %8, off offset:48 sc0 sc1\n\t"
        "global_load_dwordx4 %4, %8, off offset:64 sc0 sc1\n\t"
        "global_load_dwordx4 %5, %8, off offset:80 sc0 sc1\n\t"
        "global_load_dwordx4 %6, %8, off offset:96 sc0 sc1\n\t"
        "global_load_dwordx4 %7, %8, off offset:112 sc0 sc1\n\t"
        "s_waitcnt vmcnt(0)"
        : "=&v"(a[0]), "=&v"(a[1]), "=&v"(a[2]), "=&v"(a[3]),
          "=&v"(a[4]), "=&v"(a[5]), "=&v"(a[6]), "=&v"(a[7])
        : "v"(p) : "memory");
}
// poll until all 32 dwords carry `tag` in their low byte
__device__ __forceinline__ void poll_h32(const float* p, unsigned tag, f32x4 (&hv)[8]) {
    unsigned m;
    do {
        coh_load_h32(p, hv);
        m = 0;
#pragma unroll
        for (int i = 0; i < 8; ++i)
#pragma unroll
            for (int j = 0; j < 4; ++j)
                m |= (__float_as_uint(hv[i][j]) ^ tag);
    } while (m & 0xFFu);
}
__device__ __forceinline__ float untag(float v) {
    return __uint_as_float(__float_as_uint(v) & 0xFFFFFF00u);
}

// ---------------- LSTM layer 1 (input = clipped x, fused maxpool) ----------
__global__ __launch_bounds__(512, 2) void lstm1_kernel(
    const float* __restrict__ x, const int* __restrict__ x_len,
    const float* __restrict__ Wk_s, const float* __restrict__ Wr_s, const float* __restrict__ b_s,
    const float* __restrict__ Wk_c, const float* __restrict__ Wr_c, const float* __restrict__ b_c,
    float* __restrict__ hbuf,          // [2][64][256] (zeroed -> h=0, tag=0)
    float* __restrict__ pooled)        // [2][32][342][256]
{
    const int blk = blockIdx.x;        // 0..255
    const int q   = blk >> 6;          // quarter 0..3
    const int grp = blk & 63;          // (branch, sample)
    const int br  = grp >> 5;
    const int s   = grp & 31;
    const int tid = threadIdx.x;
    const int u   = tid & 63;          // unit within quarter
    const int rg  = tid >> 6;          // row-group 0..7 (32 h-rows each)
    const int col0 = q * 64 + u;       // output unit index within H

    const float* Wk = br ? Wk_c : Wk_s;
    const float* Wr = br ? Wr_c : Wr_s;
    const float* bb = br ? b_c  : b_s;

    // Recurrent weight slice: w[g][k] = Wr[rg*32+k][g*256+col0]
    float w[4][32];
#pragma unroll
    for (int g = 0; g < 4; ++g)
#pragma unroll
        for (int k = 0; k < 32; ++k)
            w[g][k] = Wr[(size_t)(rg * 32 + k) * 1024 + g * 256 + col0];

    // Input-kernel slice: rows rg*8..rg*8+7 (rg<5 covers F=40)
    float wk[4][8];
    if (rg < 5) {
#pragma unroll
        for (int g = 0; g < 4; ++g)
#pragma unroll
            for (int j = 0; j < 8; ++j)
                wk[g][j] = Wk[(size_t)(rg * 8 + j) * 1024 + g * 256 + col0];
    }

    float bias[4] = {0.f, 0.f, 0.f, 0.f};
    if (rg == 0) {
#pragma unroll
        for (int g = 0; g < 4; ++g) bias[g] = bb[g * 256 + col0];
    }

    const int len = x_len[s];
    float cst = 0.f, hcur = 0.f, pm = -1e30f;

    __shared__ float part[2][8][4][64];   // step-parity double buffer

    for (int t = 0; t < TT; ++t) {
        if (t < len) {
            // 1) independent input contribution (off critical path)
            float acc[4] = {0.f, 0.f, 0.f, 0.f};
            if (rg < 5) {
                const float* xr = x + ((size_t)s * TT + t) * FF + rg * 8;
#pragma unroll
                for (int j = 0; j < 8; ++j) {
                    float v = xr[j];
                    v = fminf(fmaxf(v, -3.f), 3.f);   // clip(x,-3,3)
#pragma unroll
                    for (int g = 0; g < 4; ++g) acc[g] += v * wk[g][j];
                }
            }
            // 2) poll my 32 h rows of step t (tag = t&0xFF rides in the data)
            const float* hr = hbuf + ((size_t)(t & 1) * 64 + grp) * 256 + rg * 32;
            f32x4 hv[8];
            poll_h32(hr, (unsigned)t & 0xFFu, hv);

            // 3) partial z for my rows (mask tag bits off before use)
#pragma unroll
            for (int i = 0; i < 8; ++i) {
#pragma unroll
                for (int jj = 0; jj < 4; ++jj) {
                    float hh = untag(hv[i][jj]);
#pragma unroll
                    for (int g = 0; g < 4; ++g)
                        acc[g] += hh * w[g][i * 4 + jj];
                }
            }
#pragma unroll
            for (int g = 0; g < 4; ++g) part[t & 1][rg][g][u] = acc[g];
            __syncthreads();

            // 4) gate math + publish h quarter (wave rg==0 only)
            if (rg == 0) {
                float z[4];
#pragma unroll
                for (int g = 0; g < 4; ++g) {
                    float sum = bias[g];
#pragma unroll
                    for (int r = 0; r < 8; ++r) sum += part[t & 1][r][g][u];
                    z[g] = sum;
                }
                float ig = sigf(z[0]);
                float fg = sigf(z[1]);
                float gg = tanhfast(z[2]);
                float og = sigf(z[3]);
                cst  = fg * cst + ig * gg;
                hcur = og * tanhfast(cst);
                float* hw = hbuf + ((size_t)((t + 1) & 1) * 64 + grp) * 256;
                unsigned hb = (__float_as_uint(hcur) & 0xFFFFFF00u)
                            | ((unsigned)(t + 1) & 0xFFu);
                coh_store_u32((unsigned*)(hw + col0), hb);   // no wait, no flag
            }
            // no second __syncthreads: part[] is parity double-buffered
        }
        // fused maxpool3 stride3 SAME: window t' covers t in {3t'-1, 3t', 3t'+1}
        if (rg == 0) {
            pm = fmaxf(pm, hcur);
            if ((t % 3) == 1) {
                int tp = (t - 1) / 3;
                pooled[(((size_t)br * 32 + s) * TP + tp) * HID + col0] = pm;
                pm = -1e30f;
            }
        }
    }
    if (rg == 0)   // final window t'=341 covers t=1022,1023
        pooled[(((size_t)br * 32 + s) * TP + 341) * HID + col0] = pm;
}

// ---------------- LSTM layers 2/3 (input projection precomputed) -----------
__global__ __launch_bounds__(512, 2) void lstm23_kernel(
    const float* __restrict__ xz,      // [2][32][342][1024] (bias folded in)
    const int* __restrict__ x_len,
    const float* __restrict__ Wr_s, const float* __restrict__ Wr_c,
    float* __restrict__ hbuf,
    float* __restrict__ yout)          // [2][32][342][256]
{
    const int blk = blockIdx.x;
    const int q   = blk >> 6;
    const int grp = blk & 63;
    const int br  = grp >> 5;
    const int s   = grp & 31;
    const int tid = threadIdx.x;
    const int u   = tid & 63;
    const int rg  = tid >> 6;
    const int col0 = q * 64 + u;

    const float* Wr = br ? Wr_c : Wr_s;

    float w[4][32];
#pragma unroll
    for (int g = 0; g < 4; ++g)
#pragma unroll
        for (int k = 0; k < 32; ++k)
            w[g][k] = Wr[(size_t)(rg * 32 + k) * 1024 + g * 256 + col0];

    const int len = (x_len[s] + 2) / 3;   // seq_len after pool
    float cst = 0.f, hcur = 0.f;

    __shared__ float part[2][8][4][64];

    for (int t = 0; t < TP; ++t) {
        const size_t row = ((size_t)br * 32 + s) * TP + t;
        if (t < len) {
            // independent input projection (rg==0 lanes) — issue before poll
            float xzv[4] = {0.f, 0.f, 0.f, 0.f};
            if (rg == 0) {
#pragma unroll
                for (int g = 0; g < 4; ++g)
                    xzv[g] = xz[row * 1024 + g * 256 + col0];
            }
            const float* hr = hbuf + ((size_t)(t & 1) * 64 + grp) * 256 + rg * 32;
            f32x4 hv[8];
            poll_h32(hr, (unsigned)t & 0xFFu, hv);

            float acc[4] = {0.f, 0.f, 0.f, 0.f};
#pragma unroll
            for (int i = 0; i < 8; ++i) {
#pragma unroll
                for (int jj = 0; jj < 4; ++jj) {
                    float hh = untag(hv[i][jj]);
#pragma unroll
                    for (int g = 0; g < 4; ++g)
                        acc[g] += hh * w[g][i * 4 + jj];
                }
            }
#pragma unroll
            for (int g = 0; g < 4; ++g) part[t & 1][rg][g][u] = acc[g];
            __syncthreads();

            if (rg == 0) {
                float z[4];
#pragma unroll
                for (int g = 0; g < 4; ++g) {
                    float sum = xzv[g];
#pragma unroll
                    for (int r = 0; r < 8; ++r) sum += part[t & 1][r][g][u];
                    z[g] = sum;
                }
                float ig = sigf(z[0]);
                float fg = sigf(z[1]);
                float gg = tanhfast(z[2]);
                float og = sigf(z[3]);
                cst  = fg * cst + ig * gg;
                hcur = og * tanhfast(cst);
                float* hw = hbuf + ((size_t)((t + 1) & 1) * 64 + grp) * 256;
                unsigned hb = (__float_as_uint(hcur) & 0xFFFFFF00u)
                            | ((unsigned)(t + 1) & 0xFFu);
                coh_store_u32((unsigned*)(hw + col0), hb);
            }
        }
        if (rg == 0)
            yout[row * HID + col0] = hcur;   // carried value when masked
    }
}

// ---------------- xz = A @ Wk + b (per-branch weights) ---------------------
// A: (21888, 256) rows 0..10943 branch s, 10944.. branch c. out: (21888, 1024)
__global__ __launch_bounds__(256) void gemm_xz(
    const float* __restrict__ A,
    const float* __restrict__ Ws, const float* __restrict__ Wc,
    const float* __restrict__ bs, const float* __restrict__ bc,
    float* __restrict__ out)
{
    __shared__ float As[32][68];    // [k][m], padded
    __shared__ float Bs[32][132];   // [k][n], padded
    const int tid = threadIdx.x;
    const int bx = blockIdx.x, by = blockIdx.y;   // 8 x 342
    const int row0 = by * 64, col0 = bx * 128;
    const int br = (by >= 171);
    const float* W    = br ? Wc : Ws;
    const float* bias = br ? bc : bs;
    const int tx = tid & 15, ty = tid >> 4;

    float acc[4][8];
#pragma unroll
    for (int i = 0; i < 4; ++i)
#pragma unroll
        for (int j = 0; j < 8; ++j) acc[i][j] = 0.f;

    for (int k0 = 0; k0 < 256; k0 += 32) {
#pragma unroll
        for (int i = 0; i < 2; ++i) {              // A tile 64x32, store transposed
            int c = tid * 2 + i;
            int r = c >> 3, kv = c & 7;
            float4 v = *(const float4*)(A + (size_t)(row0 + r) * 256 + k0 + kv * 4);
            As[kv * 4 + 0][r] = v.x; As[kv * 4 + 1][r] = v.y;
            As[kv * 4 + 2][r] = v.z; As[kv * 4 + 3][r] = v.w;
        }
#pragma unroll
        for (int i = 0; i < 4; ++i) {              // B tile 32x128
            int c = tid + i * 256;
            int kr = c >> 5, nv = c & 31;
            *(float4*)&Bs[kr][nv * 4] =
                *(const float4*)(W + (size_t)(k0 + kr) * 1024 + col0 + nv * 4);
        }
        __syncthreads();
#pragma unroll
        for (int k = 0; k < 32; ++k) {
            float4 a  = *(const float4*)&As[k][ty * 4];
            float4 b0 = *(const float4*)&Bs[k][tx * 8];
            float4 b1 = *(const float4*)&Bs[k][tx * 8 + 4];
            float av[4] = {a.x, a.y, a.z, a.w};
            float bv[8] = {b0.x, b0.y, b0.z, b0.w, b1.x, b1.y, b1.z, b1.w};
#pragma unroll
            for (int i = 0; i < 4; ++i)
#pragma unroll
                for (int j = 0; j < 8; ++j)
                    acc[i][j] += av[i] * bv[j];
        }
        __syncthreads();
    }
    float bv[8];
#pragma unroll
    for (int j = 0; j < 8; ++j) bv[j] = bias[col0 + tx * 8 + j];
#pragma unroll
    for (int i = 0; i < 4; ++i) {
        int r = row0 + ty * 4 + i;
        float4 o0 = {acc[i][0] + bv[0], acc[i][1] + bv[1], acc[i][2] + bv[2], acc[i][3] + bv[3]};
        float4 o1 = {acc[i][4] + bv[4], acc[i][5] + bv[5], acc[i][6] + bv[6], acc[i][7] + bv[7]};
        float* po = out + (size_t)r * 1024 + col0 + tx * 8;
        *(float4*)(po)     = o0;
        *(float4*)(po + 4) = o1;
    }
}

// ---------------- CTC projection -------------------------------------------
__global__ __launch_bounds__(256) void ctc_kernel(
    const float* __restrict__ Y,      // (21888, 256)
    const float* __restrict__ Wct,    // (256, 30)
    const float* __restrict__ bct,    // (30)
    float* __restrict__ dout)
{
    __shared__ float wl[256 * 30];
    __shared__ float yl[8][257];
    const int tid = threadIdx.x;
    const int row0 = blockIdx.x * 8;

    for (int i = tid; i < 7680; i += 256) wl[i] = Wct[i];
#pragma unroll
    for (int i = 0; i < 8; ++i) {
        int c = tid + i * 256;
        int r = c >> 8, k = c & 255;
        yl[r][k] = Y[(size_t)(row0 + r) * 256 + k];
    }
    __syncthreads();

    const int v = tid & 31, r = tid >> 5;
    if (v < 30) {
        float acc = bct[v];
#pragma unroll 8
        for (int k = 0; k < 256; ++k) acc += yl[r][k] * wl[k * 30 + v];
        int gr = row0 + r;
        int br = gr / 10944;
        int rr = gr - br * 10944;
        dout[(br ? 328352 : 0) + (size_t)rr * 30 + v] = acc;
    }
}

// ---------------- lens + close flags ----------------------------------------
__global__ __launch_bounds__(256) void finalize_kernel(
    const int* __restrict__ x_len, float* __restrict__ dout)
{
    const int b = blockIdx.x, tid = threadIdx.x;
    const float* cs = dout + (size_t)b * 10260;
    const float* cc = dout + 328352 + (size_t)b * 10260;
    __shared__ int flag;
    if (tid == 0) flag = 1;
    __syncthreads();
    bool ok = true;
    for (int i = tid; i < 10260; i += 256)
        ok &= (fabsf(cs[i] - cc[i]) < 1e-5f);
    if (!ok) atomicAnd(&flag, 0);
    __syncthreads();
    if (tid == 0) {
        float L = (float)((x_len[b] + 2) / 3);
        dout[328320 + b] = L;          // len_s
        dout[656672 + b] = L;          // len_c
        dout[656704 + b] = flag ? 1.0f : 0.0f;  // close
    }
}

// ---------------------------------------------------------------------------
extern "C" void kernel_launch(void* const* d_in, const int* in_sizes, int n_in,
                              void* d_out, int out_size, void* d_ws, size_t ws_size,
                              hipStream_t stream)
{
    (void)in_sizes; (void)n_in; (void)out_size;
    const float* x     = (const float*)d_in[0];
    const int*   x_len = (const int*)  d_in[1];
    const float* ws0_k = (const float*)d_in[2];
    const float* ws0_r = (const float*)d_in[3];
    const float* ws0_b = (const float*)d_in[4];
    const float* ws1_k = (const float*)d_in[5];
    const float* ws1_r = (const float*)d_in[6];
    const float* ws1_b = (const float*)d_in[7];
    const float* wc0_k = (const float*)d_in[8];
    const float* wc0_r = (const float*)d_in[9];
    const float* wc0_b = (const float*)d_in[10];
    const float* wc1_k = (const float*)d_in[11];
    const float* wc1_r = (const float*)d_in[12];
    const float* wc1_b = (const float*)d_in[13];
    const float* ctc_w = (const float*)d_in[14];
    const float* ctc_b = (const float*)d_in[15];
    float* out = (float*)d_out;
    char*  ws  = (char*)d_ws;

    // workspace layout
    const size_t h_bytes  = 3ull * 2 * 64 * 256 * sizeof(float);      // 393216
    const size_t off_b0   = h_bytes;
    const size_t b0_bytes = 2ull * 32 * 342 * 256 * sizeof(float);    // 22.4 MB (pooled/ys2/ys3)
    const size_t off_b1   = off_b0 + b0_bytes;
    const size_t b1_bytes = 2ull * 32 * 342 * 1024 * sizeof(float);   // 89.7 MB (xz)
    if (ws_size < off_b1 + b1_bytes) return;   // need ~112 MB

    float* h1 = (float*)ws;
    float* h2 = h1 + 2 * 64 * 256;
    float* h3 = h2 + 2 * 64 * 256;
    float* buf0 = (float*)(ws + off_b0);
    float* buf1 = (float*)(ws + off_b1);

    // zero h double-buffers (h=0, tag=0 for t=0) — fresh every launch/replay
    hipMemsetAsync(ws, 0, h_bytes, stream);

    // LSTM1 + fused maxpool -> buf0 = pooled
    lstm1_kernel<<<256, 512, 0, stream>>>(x, x_len, ws0_k, ws0_r, ws0_b,
                                          wc0_k, wc0_r, wc0_b, h1, buf0);
    // xz2 = pooled @ Wk1 + b1 -> buf1
    gemm_xz<<<dim3(8, 342), 256, 0, stream>>>(buf0, ws1_k, wc1_k, ws1_b, wc1_b, buf1);
    // LSTM2 -> buf0 = ys2
    lstm23_kernel<<<256, 512, 0, stream>>>(buf1, x_len, ws1_r, wc1_r, h2, buf0);
    // xz3 = ys2 @ Wk1 + b1 -> buf1
    gemm_xz<<<dim3(8, 342), 256, 0, stream>>>(buf0, ws1_k, wc1_k, ws1_b, wc1_b, buf1);
    // LSTM3 -> buf0 = ys3
    lstm23_kernel<<<256, 512, 0, stream>>>(buf1, x_len, ws1_r, wc1_r, h3, buf0);
    // CTC projection -> d_out ctc regions
    ctc_kernel<<<2736, 256, 0, stream>>>(buf0, ctc_w, ctc_b, out);
    // lens + close
    finalize_kernel<<<32, 256, 0, stream>>>(x_len, out);
}